// Round 1
// 162.518 us; speedup vs baseline: 1.1120x; 1.1120x over previous
//
#include <hip/hip_runtime.h>
#include <math.h>

typedef float f32x2 __attribute__((ext_vector_type(2)));
typedef float f32x4 __attribute__((ext_vector_type(4)));

// Problem constants (setup_inputs fixed: 1x3x2048x2048 fp32)
#define HH    2048
#define WW    2048
#define NCH   3
#define NOUT  2038          // 2048 - 10 (VALID 11-tap twice)
#define OWID  64            // strip width
#define OH    128           // strip height (outputs per block)
#define CROWS 16            // chunk rows
#define BUF   28            // circular h-blur buffer slots (26 live max, mod-28)
#define HAW   66            // hbA/hbB stride in pairs: 528B rows (R7-proven, b64 2-way free)
#define HCW   68            // hbC stride in floats: 272B rows
#define NTX   32            // 2048/64
#define NTY   16            // 2048/128
#define NBLOCKS (NTX*NTY*NCH)   // 1536
#define NOUT_TOTAL 12460332.0f  // 3 * 2038 * 2038

// SSIM per-pixel term. Scalar args, compile-time indices at call sites only
// (runtime pointer-select of register arrays caused scratch demotion in R2).
// rcpf: denominators >= 9e-4, rel err ~1e-6 vs 2e-2 threshold.
__device__ __forceinline__ float ssim_term(float mu1, float mu2,
                                           float b11, float b22, float b12) {
    const float c1v = 1e-4f, c2v = 9e-4f;
    float mu1sq = mu1 * mu1;
    float mu2sq = mu2 * mu2;
    float mu12  = mu1 * mu2;
    float s11 = b11 - mu1sq;
    float s22 = b22 - mu2sq;
    float s12 = b12 - mu12;
    float csn = 2.f * s12 + c2v;
    float csd = s11 + s22 + c2v;
    float ln  = 2.f * mu12 + c1v;
    float ld  = mu1sq + mu2sq + c1v;
    return (csn * ln) * __builtin_amdgcn_rcpf(csd * ld);
}

// R9: latency/barrier-bound fix. (a) sxy staging + stage A removed: each blur
// thread loads its own 14-col halo from global (L1/L2 serve the 3.5x overlap,
// HBM unchanged). (b) ring 32->28 slots (26 live max, stay-16-ahead schedule)
// -> LDS 52.7->37.2 KB -> 4 blocks/CU (was 3). (c) global loads for chunk m
// issued BEFORE stage C(m), consumed in blur after the barrier: HBM latency
// hides under ~800cy of v-blur compute. Barriers/block 26 -> 16.
// fp32 throughout (R5 fp16 regressed). __launch_bounds__(256,2): (256,4)
// caps VGPR at 64 -> catastrophic spill (R3). VGPR budget must stay <=128
// for 16 waves/CU.
__global__ __launch_bounds__(256, 2)
void ssim_main(const float* __restrict__ x, const float* __restrict__ y,
               float* __restrict__ partials) {
    __shared__ f32x2 hbA[BUF][HAW];      // (mu1,mu2) h-blur ring: 14.4 KB
    __shared__ f32x2 hbB[BUF][HAW];      // (xx,yy)  h-blur ring: 14.4 KB
    __shared__ float hbC[BUF][HCW];      // xy       h-blur ring:  7.4 KB
    __shared__ float wsum[4];            // total 37.2 KB -> 4 blocks/CU

    const int tid = threadIdx.x;
    const int gx0 = blockIdx.x * OWID;
    const int gy0 = blockIdx.y * OH;
    const float* xb = x + (size_t)blockIdx.z * HH * WW;
    const float* yb = y + (size_t)blockIdx.z * HH * WW;

    // Gaussian weights (11 taps, sigma 1.5), normalized — matches jnp f32
    float w[11];
    {
        float s = 0.f;
        #pragma unroll
        for (int i = 0; i < 11; ++i) {
            float d = (float)(i - 5);
            w[i] = expf(-d * d / 4.5f);
            s += w[i];
        }
        float inv = 1.f / s;
        #pragma unroll
        for (int i = 0; i < 11; ++i) w[i] *= inv;
    }

    // h-blur geometry: thread (lr, c0) produces ring row lr, pair cols
    // [c0, c0+4) from input cols [c0, c0+14).
    const int lr  = tid >> 4;            // 0..15
    const int c0  = (tid & 15) * 4;      // 0..60
    const int gxc = gx0 + c0;

    // Prefetch registers: 14 input cols x 2 images = 28 VGPRs, live across C.
    f32x4 px[3], py[3];
    f32x2 px3, py3;

    // Issue the global loads for h-rows [base, base+16) (this thread's slice).
    auto PF = [&](int base) {
        int gy = gy0 + base + lr; if (gy > HH - 1) gy = HH - 1;
        const float* xr = xb + (size_t)gy * WW;
        const float* yr = yb + (size_t)gy * WW;
        #pragma unroll
        for (int a = 0; a < 3; ++a) {
            int g = gxc + 4 * a;
            if (g + 4 <= WW) {
                px[a] = *(const f32x4*)(xr + g);
                py[a] = *(const f32x4*)(yr + g);
            } else {  // right-edge clamp; feeds only guarded outputs
                int g0 = g     < WW ? g     : WW - 1;
                int g1 = g + 1 < WW ? g + 1 : WW - 1;
                int g2 = g + 2 < WW ? g + 2 : WW - 1;
                int g3 = g + 3 < WW ? g + 3 : WW - 1;
                px[a] = (f32x4){xr[g0], xr[g1], xr[g2], xr[g3]};
                py[a] = (f32x4){yr[g0], yr[g1], yr[g2], yr[g3]};
            }
        }
        {
            int g = gxc + 12;
            if (g + 2 <= WW) {
                px3 = *(const f32x2*)(xr + g);
                py3 = *(const f32x2*)(yr + g);
            } else {
                int g0 = g     < WW ? g     : WW - 1;
                int g1 = g + 1 < WW ? g + 1 : WW - 1;
                px3 = (f32x2){xr[g0], xr[g1]};
                py3 = (f32x2){yr[g0], yr[g1]};
            }
        }
    };

    // h-blur the prefetched row into ring slot (base+lr)%28.
    // Per tap per col: 2 pk_fma + 1 fma. tailMask: prologue partial chunk
    // (rows [16,26)) — threads lr>=10 compute but must not store (their slot
    // would alias live rows).
    auto BLUR = [&](int base, bool tailMask) {
        int slot = (base + lr) % BUF;
        f32x2 p[14];
        #pragma unroll
        for (int a = 0; a < 3; ++a)
            #pragma unroll
            for (int i = 0; i < 4; ++i)
                p[4 * a + i] = (f32x2){px[a][i], py[a][i]};
        p[12] = (f32x2){px3.x, py3.x};
        p[13] = (f32x2){px3.y, py3.y};
        f32x2 q[14]; float pr[14];
        #pragma unroll
        for (int t = 0; t < 14; ++t) {
            q[t]  = p[t] * p[t];             // v_pk_mul_f32
            pr[t] = p[t].x * p[t].y;
        }
        f32x2 hA[4] = {}, hB[4] = {};
        float hC[4] = {};
        #pragma unroll
        for (int k = 0; k < 11; ++k) {
            f32x2 wk2 = (f32x2){w[k], w[k]};
            #pragma unroll
            for (int j = 0; j < 4; ++j) {
                hA[j] = __builtin_elementwise_fma(wk2, p[j + k], hA[j]);
                hB[j] = __builtin_elementwise_fma(wk2, q[j + k], hB[j]);
                hC[j] = fmaf(w[k], pr[j + k], hC[j]);
            }
        }
        if (!tailMask || lr < 10) {
            // b128 stores (rows 528B/272B, c0 mult of 4 -> 16B-aligned)
            *(f32x4*)&hbA[slot][c0]     = (f32x4){hA[0].x, hA[0].y, hA[1].x, hA[1].y};
            *(f32x4*)&hbA[slot][c0 + 2] = (f32x4){hA[2].x, hA[2].y, hA[3].x, hA[3].y};
            *(f32x4*)&hbB[slot][c0]     = (f32x4){hB[0].x, hB[0].y, hB[1].x, hB[1].y};
            *(f32x4*)&hbB[slot][c0 + 2] = (f32x4){hB[2].x, hB[2].y, hB[3].x, hB[3].y};
            *(float4*)&hbC[slot][c0]    = make_float4(hC[0], hC[1], hC[2], hC[3]);
        }
    };

    float partial = 0.f;

    // Prologue: h-rows [0,26) into the ring (26 live = max).
    PF(0);  BLUR(0, false);
    PF(16); BLUR(16, true);
    __syncthreads();

    const int col  = tid & 63;
    const int wid  = tid >> 6;           // wave id -> slot math is wave-uniform
    const int ocol = gx0 + col;

    // Main loop: 8 chunks of 16 output rows. Invariant before C(m): ring holds
    // h-rows [16m, 16m+26). C(m) consumes the window; after the barrier, BLUR
    // overwrites the 16 dead slots (rows 16m+26..16m+42 land on rows-28 slots).
    for (int m = 0; m < 8; ++m) {
        if (m < 7) PF(16 * m + 26);      // in flight during stage C
        {   // Stage C: v-blur, 1 col x 4 rows per thread, sliding window:
            // read ring row once, feed its <=4 output accumulators. FP order
            // per output is k ascending — identical to the batched version.
            const int r0 = 16 * m + wid * 4;
            int s = r0 % BUF;
            f32x2 aA[4] = {}, aB[4] = {};
            float aC[4] = {};
            #pragma unroll
            for (int j = 0; j < 14; ++j) {
                f32x2 va = hbA[s][col];
                f32x2 vb = hbB[s][col];
                float vc = hbC[s][col];
                #pragma unroll
                for (int i = 0; i < 4; ++i) {
                    const int k = j - i;
                    if (k >= 0 && k < 11) {
                        f32x2 wk2 = (f32x2){w[k], w[k]};
                        aA[i] = __builtin_elementwise_fma(wk2, va, aA[i]);
                        aB[i] = __builtin_elementwise_fma(wk2, vb, aB[i]);
                        aC[i] = fmaf(w[k], vc, aC[i]);
                    }
                }
                s = (s == BUF - 1) ? 0 : s + 1;
            }
            #pragma unroll
            for (int i = 0; i < 4; ++i) {
                int orow = gy0 + r0 + i;
                if (orow < NOUT && ocol < NOUT)
                    partial += ssim_term(aA[i].x, aA[i].y, aB[i].x, aB[i].y, aC[i]);
            }
        }
        __syncthreads();                 // C reads done before BLUR overwrites
        if (m < 7) {
            BLUR(16 * m + 26, false);
            __syncthreads();             // ring writes visible for next C
        }
    }

    // Reduction: wave shuffle -> block -> one plain store per block.
    #pragma unroll
    for (int off = 32; off > 0; off >>= 1)
        partial += __shfl_down(partial, off, 64);
    if ((tid & 63) == 0) wsum[tid >> 6] = partial;
    __syncthreads();
    if (tid == 0) {
        int bid = (blockIdx.z * gridDim.y + blockIdx.y) * gridDim.x + blockIdx.x;
        partials[bid] = wsum[0] + wsum[1] + wsum[2] + wsum[3];
    }
}

__global__ __launch_bounds__(256)
void ssim_finalize(const float* __restrict__ partials, float* __restrict__ out) {
    __shared__ float ws[4];
    float s = 0.f;
    // NBLOCKS = 1536 = 384 float4s
    for (int i = threadIdx.x; i < NBLOCKS / 4; i += 256) {
        float4 v = ((const float4*)partials)[i];
        s += (v.x + v.y) + (v.z + v.w);
    }
    #pragma unroll
    for (int off = 32; off > 0; off >>= 1)
        s += __shfl_down(s, off, 64);
    if ((threadIdx.x & 63) == 0) ws[threadIdx.x >> 6] = s;
    __syncthreads();
    if (threadIdx.x == 0)
        out[0] = 1.f - (ws[0] + ws[1] + ws[2] + ws[3]) / NOUT_TOTAL;
}

extern "C" void kernel_launch(void* const* d_in, const int* in_sizes, int n_in,
                              void* d_out, int out_size, void* d_ws, size_t ws_size,
                              hipStream_t stream) {
    const float* x = (const float*)d_in[0];
    const float* y = (const float*)d_in[1];
    float* out = (float*)d_out;
    float* partials = (float*)d_ws;   // NBLOCKS floats = 6 KB of scratch

    dim3 grid(NTX, NTY, NCH);
    ssim_main<<<grid, dim3(256), 0, stream>>>(x, y, partials);
    ssim_finalize<<<1, 256, 0, stream>>>(partials, out);
}